// Round 1
// baseline (1216.914 us; speedup 1.0000x reference)
//
#include <hip/hip_runtime.h>
#include <math.h>

#define Nn 102400
#define Gg 256
#define Pp 400
#define Ee 3276800
#define Ff 128
#define Kk 30
#define Cc 97

// ---------------- CSR build ----------------
__global__ void k_count(const int* __restrict__ ei, int* __restrict__ cnt) {
    int e = blockIdx.x * 256 + threadIdx.x;
    if (e >= Ee) return;
    int s = ei[e], d = ei[Ee + e];
    if (s != d) atomicAdd(&cnt[d], 1);
}

__global__ void k_dis(const int* __restrict__ cnt, float* __restrict__ dis) {
    int n = blockIdx.x * 256 + threadIdx.x;
    if (n < Nn) dis[n] = rsqrtf((float)cnt[n] + 1.0f);
}

// one block, 1024 threads; thread t owns 100 contiguous rows
__global__ void k_scan(const int* __restrict__ cnt, int* __restrict__ row_start,
                       int* __restrict__ cursor) {
    __shared__ int tot[1024];
    int t = threadIdx.x;
    int base = t * 100;
    int s = 0;
    for (int i = 0; i < 100; i++) s += cnt[base + i];
    tot[t] = s;
    __syncthreads();
    for (int off = 1; off < 1024; off <<= 1) {
        int v = (t >= off) ? tot[t - off] : 0;
        __syncthreads();
        tot[t] += v;
        __syncthreads();
    }
    int run = tot[t] - s;  // exclusive prefix for this chunk
    for (int i = 0; i < 100; i++) {
        row_start[base + i] = run;
        cursor[base + i] = run;
        run += cnt[base + i];
    }
}

__global__ void k_scatter(const int* __restrict__ ei, int* __restrict__ cursor,
                          int* __restrict__ col) {
    int e = blockIdx.x * 256 + threadIdx.x;
    if (e >= Ee) return;
    int s = ei[e], d = ei[Ee + e];
    if (s != d) { int pos = atomicAdd(&cursor[d], 1); col[pos] = s; }
}

// ---------------- GCN layers ----------------
// g[n][c] = dis[n] * sum_k h[n][k] * W[k][c]
__global__ void k_gemm128x32(const float* __restrict__ h, const float* __restrict__ W,
                             const float* __restrict__ dis, float* __restrict__ g) {
    __shared__ float Wl[128 * 32];
    __shared__ float hrow[8][128];
    int tid = threadIdx.x;
    for (int i = tid; i < 128 * 32; i += 256) Wl[i] = W[i];
    int grp = tid >> 5, c = tid & 31;
    int n = blockIdx.x * 8 + grp;
    for (int q = 0; q < 4; q++) hrow[grp][c + 32 * q] = h[n * 128 + c + 32 * q];
    __syncthreads();
    float acc = 0.f;
#pragma unroll 8
    for (int k = 0; k < 128; k++) acc += hrow[grp][k] * Wl[k * 32 + c];
    g[n * 32 + c] = dis[n] * acc;
}

__global__ void k_gemm32x32(const float* __restrict__ h, const float* __restrict__ W,
                            const float* __restrict__ dis, float* __restrict__ g) {
    __shared__ float Wl[32 * 32];
    __shared__ float hrow[8][32];
    int tid = threadIdx.x;
    for (int i = tid; i < 1024; i += 256) Wl[i] = W[i];
    int grp = tid >> 5, c = tid & 31;
    int n = blockIdx.x * 8 + grp;
    hrow[grp][c] = h[n * 32 + c];
    __syncthreads();
    float acc = 0.f;
#pragma unroll
    for (int k = 0; k < 32; k++) acc += hrow[grp][k] * Wl[k * 32 + c];
    g[n * 32 + c] = dis[n] * acc;
}

__global__ void k_gemm32x1(const float* __restrict__ h, const float* __restrict__ W,
                           const float* __restrict__ dis, float* __restrict__ g4) {
    int tid = threadIdx.x;
    int grp = tid >> 5, k = tid & 31;
    int n = blockIdx.x * 8 + grp;
    float v = h[n * 32 + k] * W[k];
#pragma unroll
    for (int m = 16; m >= 1; m >>= 1) v += __shfl_xor(v, m);
    if (k == 0) g4[n] = dis[n] * v;
}

// out[n][c] = tanh(dis[n]*(g[n][c] + sum_{e in CSR(n)} g[col[e]][c]) + b[c])
__global__ void k_agg32(const float* __restrict__ g, const int* __restrict__ row_start,
                        const int* __restrict__ cnt, const int* __restrict__ col,
                        const float* __restrict__ dis, const float* __restrict__ b,
                        float* __restrict__ out) {
    int tid = threadIdx.x;
    int grp = tid >> 5, c = tid & 31;
    int n = blockIdx.x * 8 + grp;
    float acc = g[n * 32 + c];
    int st = row_start[n], en = st + cnt[n];
    for (int e = st; e < en; e++) {
        int s = col[e];
        acc += g[s * 32 + c];
    }
    out[n * 32 + c] = tanhf(dis[n] * acc + b[c]);
}

__global__ void k_agg1(const float* __restrict__ g4, const int* __restrict__ row_start,
                       const int* __restrict__ cnt, const int* __restrict__ col,
                       const float* __restrict__ dis, const float* __restrict__ b4,
                       float* __restrict__ x4) {
    int tid = threadIdx.x;
    int grp = tid >> 6, l = tid & 63;
    int n = blockIdx.x * 4 + grp;
    int st = row_start[n], cn = cnt[n];
    float acc = 0.f;
    for (int e = l; e < cn; e += 64) acc += g4[col[st + e]];
#pragma unroll
    for (int m = 32; m >= 1; m >>= 1) acc += __shfl_xor(acc, m);
    if (l == 0) x4[n] = tanhf(dis[n] * (acc + g4[n]) + b4[0]);
}

// ---------------- sort pool ----------------
__global__ void k_sortpool(const float* __restrict__ x1, const float* __restrict__ x2,
                           const float* __restrict__ x3, const float* __restrict__ x4,
                           float* __restrict__ pooled) {
    __shared__ float vals[Pp];
    __shared__ int sel[Kk];
    int gid = blockIdx.x;
    int tid = threadIdx.x;
    for (int i = tid; i < Pp; i += 256) vals[i] = x4[gid * Pp + i];
    __syncthreads();
    for (int i = tid; i < Pp; i += 256) {
        float v = vals[i];
        int rank = 0;
        for (int j = 0; j < Pp; j++) {
            float u = vals[j];
            rank += (u > v) || (u == v && j < i);   // stable desc sort rank
        }
        if (rank < Kk) sel[rank] = i;
    }
    __syncthreads();
    for (int t = tid; t < Kk * Cc; t += 256) {
        int k = t / Cc, c = t - k * Cc;
        int n = gid * Pp + sel[k];
        float v;
        if (c < 32)      v = x1[n * 32 + c];
        else if (c < 64) v = x2[n * 32 + c - 32];
        else if (c < 96) v = x3[n * 32 + c - 64];
        else             v = x4[n];
        pooled[gid * Kk * Cc + t] = v;
    }
}

// ---------------- CNN + MLP head ----------------
__global__ void k_head(const float* __restrict__ pooled,
                       const float* __restrict__ cw5, const float* __restrict__ cb5,
                       const float* __restrict__ cw6, const float* __restrict__ cb6,
                       const float* __restrict__ fw1, const float* __restrict__ fb1,
                       const float* __restrict__ fw2, const float* __restrict__ fb2,
                       float* __restrict__ out) {
    __shared__ float seq[Kk * Cc];     // 2910
    __shared__ float w5l[16 * 97];
    __shared__ float t5[16 * 30];
    __shared__ float pl[16 * 15];
    __shared__ float w6l[32 * 16 * 5];
    __shared__ float c6f[352];
    __shared__ float h1[128];
    __shared__ float red[128];
    int gid = blockIdx.x, tid = threadIdx.x;
    for (int i = tid; i < Kk * Cc; i += 128) seq[i] = pooled[gid * Kk * Cc + i];
    for (int i = tid; i < 16 * 97; i += 128) w5l[i] = cw5[i];
    for (int i = tid; i < 2560; i += 128) w6l[i] = cw6[i];
    __syncthreads();
    // conv5 (kernel 97 stride 97 == per-row dot) + relu
    for (int idx = tid; idx < 480; idx += 128) {
        int ch = idx / 30, t = idx - ch * 30;
        float acc = cb5[ch];
        for (int i = 0; i < 97; i++) acc += w5l[ch * 97 + i] * seq[t * 97 + i];
        t5[ch * 30 + t] = fmaxf(acc, 0.f);
    }
    __syncthreads();
    // maxpool(2,2)
    for (int idx = tid; idx < 240; idx += 128) {
        int ch = idx / 15, t = idx - ch * 15;
        pl[idx] = fmaxf(t5[ch * 30 + 2 * t], t5[ch * 30 + 2 * t + 1]);
    }
    __syncthreads();
    // conv6 (16->32, k=5) + relu
    for (int idx = tid; idx < 352; idx += 128) {
        int o = idx / 11, t = idx - o * 11;
        float acc = cb6[o];
        for (int i = 0; i < 16; i++)
            for (int j = 0; j < 5; j++)
                acc += w6l[o * 80 + i * 5 + j] * pl[i * 15 + t + j];
        c6f[o * 11 + t] = fmaxf(acc, 0.f);
    }
    __syncthreads();
    // fc1 352->128 + relu
    {
        float acc = fb1[tid];
        for (int i = 0; i < 352; i++) acc += c6f[i] * fw1[i * 128 + tid];
        h1[tid] = fmaxf(acc, 0.f);
    }
    __syncthreads();
    // fc2 128->1
    red[tid] = h1[tid] * fw2[tid];
    __syncthreads();
    for (int off = 64; off >= 1; off >>= 1) {
        if (tid < off) red[tid] += red[tid + off];
        __syncthreads();
    }
    if (tid == 0) out[gid] = red[0] + fb2[0];
}

extern "C" void kernel_launch(void* const* d_in, const int* in_sizes, int n_in,
                              void* d_out, int out_size, void* d_ws, size_t ws_size,
                              hipStream_t stream) {
    const float* x   = (const float*)d_in[0];
    const int*   ei  = (const int*)d_in[1];
    const float* W1  = (const float*)d_in[3];
    const float* b1  = (const float*)d_in[4];
    const float* W2  = (const float*)d_in[5];
    const float* b2  = (const float*)d_in[6];
    const float* W3  = (const float*)d_in[7];
    const float* b3  = (const float*)d_in[8];
    const float* W4  = (const float*)d_in[9];
    const float* b4  = (const float*)d_in[10];
    const float* cw5 = (const float*)d_in[11];
    const float* cb5 = (const float*)d_in[12];
    const float* cw6 = (const float*)d_in[13];
    const float* cb6 = (const float*)d_in[14];
    const float* fw1 = (const float*)d_in[15];
    const float* fb1 = (const float*)d_in[16];
    const float* fw2 = (const float*)d_in[17];
    const float* fb2 = (const float*)d_in[18];
    float* out = (float*)d_out;

    char* p = (char*)d_ws;
    auto alloc = [&](size_t bytes) {
        char* r = p;
        p += (bytes + 255) & ~size_t(255);
        return r;
    };
    float* dis       = (float*)alloc((size_t)Nn * 4);
    int*   cnt       = (int*)  alloc((size_t)Nn * 4);
    int*   row_start = (int*)  alloc((size_t)Nn * 4);
    int*   cursor    = (int*)  alloc((size_t)Nn * 4);
    int*   col       = (int*)  alloc((size_t)Ee * 4);
    float* x1        = (float*)alloc((size_t)Nn * 32 * 4);
    float* x2        = (float*)alloc((size_t)Nn * 32 * 4);
    float* x3        = (float*)alloc((size_t)Nn * 32 * 4);
    float* x4        = (float*)alloc((size_t)Nn * 4);
    float* g         = (float*)alloc((size_t)Nn * 32 * 4);
    float* pooled    = (float*)alloc((size_t)Gg * Kk * Cc * 4);

    hipMemsetAsync(cnt, 0, (size_t)Nn * 4, stream);
    k_count<<<Ee / 256, 256, 0, stream>>>(ei, cnt);
    k_dis<<<Nn / 256, 256, 0, stream>>>(cnt, dis);
    k_scan<<<1, 1024, 0, stream>>>(cnt, row_start, cursor);
    k_scatter<<<Ee / 256, 256, 0, stream>>>(ei, cursor, col);

    // layer 1 (128 -> 32)
    k_gemm128x32<<<Nn / 8, 256, 0, stream>>>(x, W1, dis, g);
    k_agg32<<<Nn / 8, 256, 0, stream>>>(g, row_start, cnt, col, dis, b1, x1);
    // layer 2 (32 -> 32)
    k_gemm32x32<<<Nn / 8, 256, 0, stream>>>(x1, W2, dis, g);
    k_agg32<<<Nn / 8, 256, 0, stream>>>(g, row_start, cnt, col, dis, b2, x2);
    // layer 3 (32 -> 32)
    k_gemm32x32<<<Nn / 8, 256, 0, stream>>>(x2, W3, dis, g);
    k_agg32<<<Nn / 8, 256, 0, stream>>>(g, row_start, cnt, col, dis, b3, x3);
    // layer 4 (32 -> 1)
    k_gemm32x1<<<Nn / 8, 256, 0, stream>>>(x3, W4, dis, g);
    k_agg1<<<Nn / 4, 256, 0, stream>>>(g, row_start, cnt, col, dis, b4, x4);

    k_sortpool<<<Gg, 256, 0, stream>>>(x1, x2, x3, x4, pooled);
    k_head<<<Gg, 128, 0, stream>>>(pooled, cw5, cb5, cw6, cb6, fw1, fb1, fw2, fb2, out);
}

// Round 2
// 920.437 us; speedup vs baseline: 1.3221x; 1.3221x over previous
//
#include <hip/hip_runtime.h>
#include <math.h>

#define Nn 102400
#define Gg 256
#define Pp 400
#define Ee 3276800
#define Ff 128
#define Kk 30
#define Cc 97

#define NSB 8
#define SBCAP 2048
#define GSTRIDE (NSB * SBCAP)   // 16384 col slots per graph

// ---------------- CSR build, phase 1: bucket edges by graph ----------------
__global__ void k_bucket(const int* __restrict__ ei, int* __restrict__ bcnt,
                         unsigned* __restrict__ bucket) {
    int e = blockIdx.x * 256 + threadIdx.x;
    int s = ei[e], d = ei[Ee + e];
    if (s == d) return;
    int gph = d / Pp;
    int dloc = d - gph * Pp;
    int sb = blockIdx.x & (NSB - 1);               // ~XCD-local sub-bucket
    int pos = atomicAdd(&bcnt[(gph * NSB + sb) * 16], 1);   // 1 counter per 64B line
    if (pos < SBCAP)
        bucket[gph * GSTRIDE + sb * SBCAP + pos] = (unsigned)s | ((unsigned)dloc << 17);
}

// ---------------- CSR build, phase 2: per-graph LDS counting sort ----------------
__global__ void __launch_bounds__(1024) k_build(const int* __restrict__ bcnt,
                                                unsigned* __restrict__ bucket, /* also col out */
                                                int* __restrict__ row_start,
                                                int* __restrict__ cnt_g,
                                                float* __restrict__ dis) {
    __shared__ unsigned pairs[GSTRIDE];   // 64 KB stash
    __shared__ int cntl[Pp];
    __shared__ int curl[Pp];
    __shared__ int sc[512];
    __shared__ int sbo[NSB + 1];
    int g = blockIdx.x, t = threadIdx.x;
    if (t == 0) {
        int run = 0;
        for (int sb = 0; sb < NSB; sb++) {
            sbo[sb] = run;
            int c = bcnt[(g * NSB + sb) * 16];
            if (c > SBCAP) c = SBCAP;
            run += c;
        }
        sbo[NSB] = run;
    }
    __syncthreads();
    int tot = sbo[NSB];
    for (int sb = 0; sb < NSB; sb++) {
        int base = sbo[sb], c = sbo[sb + 1] - base;
        const unsigned* srcp = bucket + g * GSTRIDE + sb * SBCAP;
        for (int i = t; i < c; i += 1024) pairs[base + i] = srcp[i];
    }
    for (int i = t; i < Pp; i += 1024) cntl[i] = 0;
    __syncthreads();
    for (int i = t; i < tot; i += 1024) atomicAdd(&cntl[pairs[i] >> 17], 1);
    __syncthreads();
    if (t < 512) sc[t] = (t < Pp) ? cntl[t] : 0;
    __syncthreads();
    for (int off = 1; off < 512; off <<= 1) {
        int v = 0;
        if (t < 512 && t >= off) v = sc[t - off];
        __syncthreads();
        if (t < 512) sc[t] += v;
        __syncthreads();
    }
    if (t < Pp) {
        int c = cntl[t];
        int ex = sc[t] - c;
        curl[t] = ex;
        int n = g * Pp + t;
        row_start[n] = g * GSTRIDE + ex;
        cnt_g[n] = c;
        dis[n] = rsqrtf((float)c + 1.0f);
    }
    __syncthreads();
    int* col = (int*)bucket;              // safe: stash done, block-local region
    for (int i = t; i < tot; i += 1024) {
        unsigned pr = pairs[i];
        int d = pr >> 17;
        int pos = atomicAdd(&curl[d], 1);
        col[g * GSTRIDE + pos] = (int)(pr & 0x1FFFFu);
    }
}

// ---------------- GCN layers ----------------
__global__ void k_gemm128x32(const float* __restrict__ h, const float* __restrict__ W,
                             const float* __restrict__ dis, float* __restrict__ g) {
    __shared__ float Wl[128 * 32];
    __shared__ float hrow[8][128];
    int tid = threadIdx.x;
    for (int i = tid; i < 128 * 32; i += 256) Wl[i] = W[i];
    int grp = tid >> 5, c = tid & 31;
    int n = blockIdx.x * 8 + grp;
    for (int q = 0; q < 4; q++) hrow[grp][c + 32 * q] = h[n * 128 + c + 32 * q];
    __syncthreads();
    float acc = 0.f;
#pragma unroll 8
    for (int k = 0; k < 128; k++) acc += hrow[grp][k] * Wl[k * 32 + c];
    g[n * 32 + c] = dis[n] * acc;
}

__global__ void k_gemm32x32(const float* __restrict__ h, const float* __restrict__ W,
                            const float* __restrict__ dis, float* __restrict__ g) {
    __shared__ float Wl[32 * 32];
    __shared__ float hrow[8][32];
    int tid = threadIdx.x;
    for (int i = tid; i < 1024; i += 256) Wl[i] = W[i];
    int grp = tid >> 5, c = tid & 31;
    int n = blockIdx.x * 8 + grp;
    hrow[grp][c] = h[n * 32 + c];
    __syncthreads();
    float acc = 0.f;
#pragma unroll
    for (int k = 0; k < 32; k++) acc += hrow[grp][k] * Wl[k * 32 + c];
    g[n * 32 + c] = dis[n] * acc;
}

__global__ void k_gemm32x1(const float* __restrict__ h, const float* __restrict__ W,
                           const float* __restrict__ dis, float* __restrict__ g4) {
    int tid = threadIdx.x;
    int grp = tid >> 5, k = tid & 31;
    int n = blockIdx.x * 8 + grp;
    float v = h[n * 32 + k] * W[k];
#pragma unroll
    for (int m = 16; m >= 1; m >>= 1) v += __shfl_xor(v, m);
    if (k == 0) g4[n] = dis[n] * v;
}

__global__ void k_agg32(const float* __restrict__ g, const int* __restrict__ row_start,
                        const int* __restrict__ cnt, const int* __restrict__ col,
                        const float* __restrict__ dis, const float* __restrict__ b,
                        float* __restrict__ out) {
    int tid = threadIdx.x;
    int grp = tid >> 5, c = tid & 31;
    int n = blockIdx.x * 8 + grp;
    float acc = g[n * 32 + c];
    int st = row_start[n], en = st + cnt[n];
    for (int e = st; e < en; e++) {
        int s = col[e];
        acc += g[s * 32 + c];
    }
    out[n * 32 + c] = tanhf(dis[n] * acc + b[c]);
}

__global__ void k_agg1(const float* __restrict__ g4, const int* __restrict__ row_start,
                       const int* __restrict__ cnt, const int* __restrict__ col,
                       const float* __restrict__ dis, const float* __restrict__ b4,
                       float* __restrict__ x4) {
    int tid = threadIdx.x;
    int grp = tid >> 6, l = tid & 63;
    int n = blockIdx.x * 4 + grp;
    int st = row_start[n], cn = cnt[n];
    float acc = 0.f;
    for (int e = l; e < cn; e += 64) acc += g4[col[st + e]];
#pragma unroll
    for (int m = 32; m >= 1; m >>= 1) acc += __shfl_xor(acc, m);
    if (l == 0) x4[n] = tanhf(dis[n] * (acc + g4[n]) + b4[0]);
}

// ---------------- sort pool ----------------
__global__ void k_sortpool(const float* __restrict__ x1, const float* __restrict__ x2,
                           const float* __restrict__ x3, const float* __restrict__ x4,
                           float* __restrict__ pooled) {
    __shared__ float vals[Pp];
    __shared__ int sel[Kk];
    int gid = blockIdx.x;
    int tid = threadIdx.x;
    for (int i = tid; i < Pp; i += 256) vals[i] = x4[gid * Pp + i];
    __syncthreads();
    for (int i = tid; i < Pp; i += 256) {
        float v = vals[i];
        int rank = 0;
        for (int j = 0; j < Pp; j++) {
            float u = vals[j];
            rank += (u > v) || (u == v && j < i);
        }
        if (rank < Kk) sel[rank] = i;
    }
    __syncthreads();
    for (int t = tid; t < Kk * Cc; t += 256) {
        int k = t / Cc, c = t - k * Cc;
        int n = gid * Pp + sel[k];
        float v;
        if (c < 32)      v = x1[n * 32 + c];
        else if (c < 64) v = x2[n * 32 + c - 32];
        else if (c < 96) v = x3[n * 32 + c - 64];
        else             v = x4[n];
        pooled[gid * Kk * Cc + t] = v;
    }
}

// ---------------- CNN + MLP head ----------------
__global__ void k_head(const float* __restrict__ pooled,
                       const float* __restrict__ cw5, const float* __restrict__ cb5,
                       const float* __restrict__ cw6, const float* __restrict__ cb6,
                       const float* __restrict__ fw1, const float* __restrict__ fb1,
                       const float* __restrict__ fw2, const float* __restrict__ fb2,
                       float* __restrict__ out) {
    __shared__ float seq[Kk * Cc];
    __shared__ float w5l[16 * 97];
    __shared__ float t5[16 * 30];
    __shared__ float pl[16 * 15];
    __shared__ float w6l[32 * 16 * 5];
    __shared__ float c6f[352];
    __shared__ float h1[128];
    __shared__ float red[128];
    int gid = blockIdx.x, tid = threadIdx.x;
    for (int i = tid; i < Kk * Cc; i += 128) seq[i] = pooled[gid * Kk * Cc + i];
    for (int i = tid; i < 16 * 97; i += 128) w5l[i] = cw5[i];
    for (int i = tid; i < 2560; i += 128) w6l[i] = cw6[i];
    __syncthreads();
    for (int idx = tid; idx < 480; idx += 128) {
        int ch = idx / 30, t = idx - ch * 30;
        float acc = cb5[ch];
        for (int i = 0; i < 97; i++) acc += w5l[ch * 97 + i] * seq[t * 97 + i];
        t5[ch * 30 + t] = fmaxf(acc, 0.f);
    }
    __syncthreads();
    for (int idx = tid; idx < 240; idx += 128) {
        int ch = idx / 15, t = idx - ch * 15;
        pl[idx] = fmaxf(t5[ch * 30 + 2 * t], t5[ch * 30 + 2 * t + 1]);
    }
    __syncthreads();
    for (int idx = tid; idx < 352; idx += 128) {
        int o = idx / 11, t = idx - o * 11;
        float acc = cb6[o];
        for (int i = 0; i < 16; i++)
            for (int j = 0; j < 5; j++)
                acc += w6l[o * 80 + i * 5 + j] * pl[i * 15 + t + j];
        c6f[o * 11 + t] = fmaxf(acc, 0.f);
    }
    __syncthreads();
    {
        float acc = fb1[tid];
        for (int i = 0; i < 352; i++) acc += c6f[i] * fw1[i * 128 + tid];
        h1[tid] = fmaxf(acc, 0.f);
    }
    __syncthreads();
    red[tid] = h1[tid] * fw2[tid];
    __syncthreads();
    for (int off = 64; off >= 1; off >>= 1) {
        if (tid < off) red[tid] += red[tid + off];
        __syncthreads();
    }
    if (tid == 0) out[gid] = red[0] + fb2[0];
}

extern "C" void kernel_launch(void* const* d_in, const int* in_sizes, int n_in,
                              void* d_out, int out_size, void* d_ws, size_t ws_size,
                              hipStream_t stream) {
    const float* x   = (const float*)d_in[0];
    const int*   ei  = (const int*)d_in[1];
    const float* W1  = (const float*)d_in[3];
    const float* b1  = (const float*)d_in[4];
    const float* W2  = (const float*)d_in[5];
    const float* b2  = (const float*)d_in[6];
    const float* W3  = (const float*)d_in[7];
    const float* b3  = (const float*)d_in[8];
    const float* W4  = (const float*)d_in[9];
    const float* b4  = (const float*)d_in[10];
    const float* cw5 = (const float*)d_in[11];
    const float* cb5 = (const float*)d_in[12];
    const float* cw6 = (const float*)d_in[13];
    const float* cb6 = (const float*)d_in[14];
    const float* fw1 = (const float*)d_in[15];
    const float* fb1 = (const float*)d_in[16];
    const float* fw2 = (const float*)d_in[17];
    const float* fb2 = (const float*)d_in[18];
    float* out = (float*)d_out;

    char* p = (char*)d_ws;
    auto alloc = [&](size_t bytes) {
        char* r = p;
        p += (bytes + 255) & ~size_t(255);
        return r;
    };
    float*    dis       = (float*)alloc((size_t)Nn * 4);
    int*      cnt       = (int*)  alloc((size_t)Nn * 4);
    int*      row_start = (int*)  alloc((size_t)Nn * 4);
    int*      bcnt      = (int*)  alloc((size_t)Gg * NSB * 16 * 4);   // 1 counter / 64B
    unsigned* bucket    = (unsigned*)alloc((size_t)Gg * GSTRIDE * 4); // reused as col
    float*    x1        = (float*)alloc((size_t)Nn * 32 * 4);
    float*    x2        = (float*)alloc((size_t)Nn * 32 * 4);
    float*    x3        = (float*)alloc((size_t)Nn * 32 * 4);
    float*    x4        = (float*)alloc((size_t)Nn * 4);
    float*    g         = (float*)alloc((size_t)Nn * 32 * 4);
    float*    pooled    = (float*)alloc((size_t)Gg * Kk * Cc * 4);
    int*      col       = (int*)bucket;

    hipMemsetAsync(bcnt, 0, (size_t)Gg * NSB * 16 * 4, stream);
    k_bucket<<<Ee / 256, 256, 0, stream>>>(ei, bcnt, bucket);
    k_build<<<Gg, 1024, 0, stream>>>(bcnt, bucket, row_start, cnt, dis);

    // layer 1 (128 -> 32)
    k_gemm128x32<<<Nn / 8, 256, 0, stream>>>(x, W1, dis, g);
    k_agg32<<<Nn / 8, 256, 0, stream>>>(g, row_start, cnt, col, dis, b1, x1);
    // layer 2 (32 -> 32)
    k_gemm32x32<<<Nn / 8, 256, 0, stream>>>(x1, W2, dis, g);
    k_agg32<<<Nn / 8, 256, 0, stream>>>(g, row_start, cnt, col, dis, b2, x2);
    // layer 3 (32 -> 32)
    k_gemm32x32<<<Nn / 8, 256, 0, stream>>>(x2, W3, dis, g);
    k_agg32<<<Nn / 8, 256, 0, stream>>>(g, row_start, cnt, col, dis, b3, x3);
    // layer 4 (32 -> 1)
    k_gemm32x1<<<Nn / 8, 256, 0, stream>>>(x3, W4, dis, g);
    k_agg1<<<Nn / 4, 256, 0, stream>>>(g, row_start, cnt, col, dis, b4, x4);

    k_sortpool<<<Gg, 256, 0, stream>>>(x1, x2, x3, x4, pooled);
    k_head<<<Gg, 128, 0, stream>>>(pooled, cw5, cb5, cw6, cb6, fw1, fb1, fw2, fb2, out);
}

// Round 5
// 605.543 us; speedup vs baseline: 2.0096x; 1.5200x over previous
//
#include <hip/hip_runtime.h>
#include <math.h>

#define Nn 102400
#define Gg 256
#define Pp 400
#define Ee 3276800
#define Ff 128
#define Kk 30
#define Cc 97

#define NSB 8
#define SBCAP 2048
#define GSTRIDE (NSB * SBCAP)   // 16384 col slots per graph

// ---------------- CSR build, phase 1: bucket edges by graph ----------------
__global__ void k_bucket(const int* __restrict__ ei, int* __restrict__ bcnt,
                         unsigned* __restrict__ bucket) {
    int e = blockIdx.x * 256 + threadIdx.x;
    int s = ei[e], d = ei[Ee + e];
    if (s == d) return;
    int gph = d / Pp;
    int dloc = d - gph * Pp;
    int sb = blockIdx.x & (NSB - 1);               // ~XCD-local sub-bucket
    int pos = atomicAdd(&bcnt[(gph * NSB + sb) * 16], 1);   // 1 counter per 64B line
    if (pos < SBCAP)
        bucket[gph * GSTRIDE + sb * SBCAP + pos] = (unsigned)s | ((unsigned)dloc << 17);
}

// ---------------- CSR build, phase 2: per-graph LDS counting sort ----------------
__global__ void __launch_bounds__(1024) k_build(const int* __restrict__ bcnt,
                                                unsigned* __restrict__ bucket, /* also col out */
                                                int* __restrict__ row_start,
                                                int* __restrict__ cnt_g,
                                                float* __restrict__ dis) {
    __shared__ unsigned pairs[GSTRIDE];   // 64 KB stash
    __shared__ int cntl[Pp];
    __shared__ int curl[Pp];
    __shared__ int sc[512];
    __shared__ int sbo[NSB + 1];
    int g = blockIdx.x, t = threadIdx.x;
    if (t == 0) {
        int run = 0;
        for (int sb = 0; sb < NSB; sb++) {
            sbo[sb] = run;
            int c = bcnt[(g * NSB + sb) * 16];
            if (c > SBCAP) c = SBCAP;
            run += c;
        }
        sbo[NSB] = run;
    }
    __syncthreads();
    int tot = sbo[NSB];
    for (int sb = 0; sb < NSB; sb++) {
        int base = sbo[sb], c = sbo[sb + 1] - base;
        const unsigned* srcp = bucket + g * GSTRIDE + sb * SBCAP;
        for (int i = t; i < c; i += 1024) pairs[base + i] = srcp[i];
    }
    for (int i = t; i < Pp; i += 1024) cntl[i] = 0;
    __syncthreads();
    for (int i = t; i < tot; i += 1024) atomicAdd(&cntl[pairs[i] >> 17], 1);
    __syncthreads();
    if (t < 512) sc[t] = (t < Pp) ? cntl[t] : 0;
    __syncthreads();
    for (int off = 1; off < 512; off <<= 1) {
        int v = 0;
        if (t < 512 && t >= off) v = sc[t - off];
        __syncthreads();
        if (t < 512) sc[t] += v;
        __syncthreads();
    }
    if (t < Pp) {
        int c = cntl[t];
        int ex = sc[t] - c;
        curl[t] = ex;
        int n = g * Pp + t;
        row_start[n] = g * GSTRIDE + ex;
        cnt_g[n] = c;
        dis[n] = rsqrtf((float)c + 1.0f);
    }
    __syncthreads();
    int* col = (int*)bucket;              // safe: stash done, block-local region
    for (int i = t; i < tot; i += 1024) {
        unsigned pr = pairs[i];
        int d = pr >> 17;
        int pos = atomicAdd(&curl[d], 1);
        col[g * GSTRIDE + pos] = (int)(pr & 0x1FFFFu);
    }
}

// ---------------- GCN layers ----------------
__global__ void k_gemm128x32(const float* __restrict__ h, const float* __restrict__ W,
                             const float* __restrict__ dis, float* __restrict__ g) {
    __shared__ __align__(16) float Wl[128 * 32];
    __shared__ __align__(16) float hrow[8][128];
    int tid = threadIdx.x;
    for (int i = tid; i < 1024; i += 256)
        ((float4*)Wl)[i] = ((const float4*)W)[i];
    int grp = tid >> 5, c = tid & 31;
    int n = blockIdx.x * 8 + grp;
    ((float4*)hrow[grp])[c] = ((const float4*)(h + n * 128))[c];
    __syncthreads();
    float acc = 0.f;
#pragma unroll 8
    for (int k = 0; k < 128; k++) acc += hrow[grp][k] * Wl[k * 32 + c];
    g[n * 32 + c] = dis[n] * acc;
}

__global__ void k_gemm32x32(const float* __restrict__ h, const float* __restrict__ W,
                            const float* __restrict__ dis, float* __restrict__ g) {
    __shared__ float Wl[32 * 32];
    __shared__ float hrow[8][32];
    int tid = threadIdx.x;
    for (int i = tid; i < 1024; i += 256) Wl[i] = W[i];
    int grp = tid >> 5, c = tid & 31;
    int n = blockIdx.x * 8 + grp;
    hrow[grp][c] = h[n * 32 + c];
    __syncthreads();
    float acc = 0.f;
#pragma unroll
    for (int k = 0; k < 32; k++) acc += hrow[grp][k] * Wl[k * 32 + c];
    g[n * 32 + c] = dis[n] * acc;
}

__global__ void k_gemm32x1(const float* __restrict__ h, const float* __restrict__ W,
                           const float* __restrict__ dis, float* __restrict__ g4) {
    int tid = threadIdx.x;
    int grp = tid >> 5, k = tid & 31;
    int n = blockIdx.x * 8 + grp;
    float v = h[n * 32 + k] * W[k];
#pragma unroll
    for (int m = 16; m >= 1; m >>= 1) v += __shfl_xor(v, m);
    if (k == 0) g4[n] = dis[n] * v;
}

// wave-per-node gather: lane = e_sub*8 + q; 8 edges x float4(4ch) in flight.
// cn is wave-uniform, so loop trip counts are uniform; every __shfl is executed
// by all 64 lanes (shfl from an exec-masked-off lane is undefined on CDNA).
__global__ void k_agg32(const float4* __restrict__ gv, const int* __restrict__ row_start,
                        const int* __restrict__ cnt, const int* __restrict__ col,
                        const float* __restrict__ dis, const float4* __restrict__ bv,
                        float4* __restrict__ outv) {
    int tid = threadIdx.x;
    int wave = tid >> 6;
    int lane = tid & 63;
    int e_sub = lane >> 3;
    int q = lane & 7;
    int n = blockIdx.x * 4 + wave;
    int st = row_start[n], cn = cnt[n];

    int colv = (lane < cn) ? col[st + lane] : 0;   // covers up to 64 edges
    int iters = cn < 64 ? cn : 64;

    float4 a0 = make_float4(0.f, 0.f, 0.f, 0.f);
    float4 a1 = make_float4(0.f, 0.f, 0.f, 0.f);
    int base = 0;
    for (; base + 16 <= iters; base += 16) {       // uniform trip count: no divergence
        int s0 = __shfl(colv, base + e_sub);
        int s1 = __shfl(colv, base + 8 + e_sub);
        float4 v0 = gv[s0 * 8 + q];
        float4 v1 = gv[s1 * 8 + q];
        a0.x += v0.x; a0.y += v0.y; a0.z += v0.z; a0.w += v0.w;
        a1.x += v1.x; a1.y += v1.y; a1.z += v1.z; a1.w += v1.w;
    }
    if (base < iters) {                             // uniform branch; shfls wave-wide
        int i0 = base + e_sub;
        int i1 = base + 8 + e_sub;
        int s0 = __shfl(colv, i0);
        int s1 = __shfl(colv, i1);
        if (i0 < iters) {
            float4 v = gv[s0 * 8 + q];
            a0.x += v.x; a0.y += v.y; a0.z += v.z; a0.w += v.w;
        }
        if (i1 < iters) {
            float4 v = gv[s1 * 8 + q];
            a1.x += v.x; a1.y += v.y; a1.z += v.z; a1.w += v.w;
        }
    }
    for (int j = 64 + e_sub; j < cn; j += 8) {      // rare high-degree tail (no shfl)
        int s = col[st + j];
        float4 v = gv[s * 8 + q];
        a0.x += v.x; a0.y += v.y; a0.z += v.z; a0.w += v.w;
    }
    a0.x += a1.x; a0.y += a1.y; a0.z += a1.z; a0.w += a1.w;
#pragma unroll
    for (int m = 8; m <= 32; m <<= 1) {
        a0.x += __shfl_xor(a0.x, m);
        a0.y += __shfl_xor(a0.y, m);
        a0.z += __shfl_xor(a0.z, m);
        a0.w += __shfl_xor(a0.w, m);
    }
    if (e_sub == 0) {
        float4 self = gv[n * 8 + q];
        float4 bb = bv[q];
        float dn = dis[n];
        float4 r;
        r.x = tanhf(dn * (a0.x + self.x) + bb.x);
        r.y = tanhf(dn * (a0.y + self.y) + bb.y);
        r.z = tanhf(dn * (a0.z + self.z) + bb.z);
        r.w = tanhf(dn * (a0.w + self.w) + bb.w);
        outv[n * 8 + q] = r;
    }
}

__global__ void k_agg1(const float* __restrict__ g4, const int* __restrict__ row_start,
                       const int* __restrict__ cnt, const int* __restrict__ col,
                       const float* __restrict__ dis, const float* __restrict__ b4,
                       float* __restrict__ x4) {
    int tid = threadIdx.x;
    int grp = tid >> 6, l = tid & 63;
    int n = blockIdx.x * 4 + grp;
    int st = row_start[n], cn = cnt[n];
    float acc = 0.f;
    for (int e = l; e < cn; e += 64) acc += g4[col[st + e]];
#pragma unroll
    for (int m = 32; m >= 1; m >>= 1) acc += __shfl_xor(acc, m);
    if (l == 0) x4[n] = tanhf(dis[n] * (acc + g4[n]) + b4[0]);
}

// ---------------- sort pool ----------------
__global__ void k_sortpool(const float* __restrict__ x1, const float* __restrict__ x2,
                           const float* __restrict__ x3, const float* __restrict__ x4,
                           float* __restrict__ pooled) {
    __shared__ float vals[Pp];
    __shared__ int sel[Kk];
    int gid = blockIdx.x;
    int tid = threadIdx.x;
    for (int i = tid; i < Pp; i += 256) vals[i] = x4[gid * Pp + i];
    __syncthreads();
    for (int i = tid; i < Pp; i += 256) {
        float v = vals[i];
        int rank = 0;
        for (int j = 0; j < Pp; j++) {
            float u = vals[j];
            rank += (u > v) || (u == v && j < i);
        }
        if (rank < Kk) sel[rank] = i;
    }
    __syncthreads();
    for (int t = tid; t < Kk * Cc; t += 256) {
        int k = t / Cc, c = t - k * Cc;
        int n = gid * Pp + sel[k];
        float v;
        if (c < 32)      v = x1[n * 32 + c];
        else if (c < 64) v = x2[n * 32 + c - 32];
        else if (c < 96) v = x3[n * 32 + c - 64];
        else             v = x4[n];
        pooled[gid * Kk * Cc + t] = v;
    }
}

// ---------------- CNN + MLP head ----------------
__global__ void k_head(const float* __restrict__ pooled,
                       const float* __restrict__ cw5, const float* __restrict__ cb5,
                       const float* __restrict__ cw6, const float* __restrict__ cb6,
                       const float* __restrict__ fw1, const float* __restrict__ fb1,
                       const float* __restrict__ fw2, const float* __restrict__ fb2,
                       float* __restrict__ out) {
    __shared__ float seq[Kk * Cc];
    __shared__ float w5l[16 * 97];
    __shared__ float t5[16 * 30];
    __shared__ float pl[16 * 15];
    __shared__ float w6l[32 * 16 * 5];
    __shared__ float c6f[352];
    __shared__ float h1[128];
    __shared__ float red[128];
    int gid = blockIdx.x, tid = threadIdx.x;
    for (int i = tid; i < Kk * Cc; i += 128) seq[i] = pooled[gid * Kk * Cc + i];
    for (int i = tid; i < 16 * 97; i += 128) w5l[i] = cw5[i];
    for (int i = tid; i < 2560; i += 128) w6l[i] = cw6[i];
    __syncthreads();
    for (int idx = tid; idx < 480; idx += 128) {
        int ch = idx / 30, t = idx - ch * 30;
        float acc = cb5[ch];
        for (int i = 0; i < 97; i++) acc += w5l[ch * 97 + i] * seq[t * 97 + i];
        t5[ch * 30 + t] = fmaxf(acc, 0.f);
    }
    __syncthreads();
    for (int idx = tid; idx < 240; idx += 128) {
        int ch = idx / 15, t = idx - ch * 15;
        pl[idx] = fmaxf(t5[ch * 30 + 2 * t], t5[ch * 30 + 2 * t + 1]);
    }
    __syncthreads();
    for (int idx = tid; idx < 352; idx += 128) {
        int o = idx / 11, t = idx - o * 11;
        float acc = cb6[o];
        for (int i = 0; i < 16; i++)
            for (int j = 0; j < 5; j++)
                acc += w6l[o * 80 + i * 5 + j] * pl[i * 15 + t + j];
        c6f[o * 11 + t] = fmaxf(acc, 0.f);
    }
    __syncthreads();
    {
        float acc = fb1[tid];
        for (int i = 0; i < 352; i++) acc += c6f[i] * fw1[i * 128 + tid];
        h1[tid] = fmaxf(acc, 0.f);
    }
    __syncthreads();
    red[tid] = h1[tid] * fw2[tid];
    __syncthreads();
    for (int off = 64; off >= 1; off >>= 1) {
        if (tid < off) red[tid] += red[tid + off];
        __syncthreads();
    }
    if (tid == 0) out[gid] = red[0] + fb2[0];
}

extern "C" void kernel_launch(void* const* d_in, const int* in_sizes, int n_in,
                              void* d_out, int out_size, void* d_ws, size_t ws_size,
                              hipStream_t stream) {
    const float* x   = (const float*)d_in[0];
    const int*   ei  = (const int*)d_in[1];
    const float* W1  = (const float*)d_in[3];
    const float* b1  = (const float*)d_in[4];
    const float* W2  = (const float*)d_in[5];
    const float* b2  = (const float*)d_in[6];
    const float* W3  = (const float*)d_in[7];
    const float* b3  = (const float*)d_in[8];
    const float* W4  = (const float*)d_in[9];
    const float* b4  = (const float*)d_in[10];
    const float* cw5 = (const float*)d_in[11];
    const float* cb5 = (const float*)d_in[12];
    const float* cw6 = (const float*)d_in[13];
    const float* cb6 = (const float*)d_in[14];
    const float* fw1 = (const float*)d_in[15];
    const float* fb1 = (const float*)d_in[16];
    const float* fw2 = (const float*)d_in[17];
    const float* fb2 = (const float*)d_in[18];
    float* out = (float*)d_out;

    char* p = (char*)d_ws;
    auto alloc = [&](size_t bytes) {
        char* r = p;
        p += (bytes + 255) & ~size_t(255);
        return r;
    };
    float*    dis       = (float*)alloc((size_t)Nn * 4);
    int*      cnt       = (int*)  alloc((size_t)Nn * 4);
    int*      row_start = (int*)  alloc((size_t)Nn * 4);
    int*      bcnt      = (int*)  alloc((size_t)Gg * NSB * 16 * 4);
    unsigned* bucket    = (unsigned*)alloc((size_t)Gg * GSTRIDE * 4); // reused as col
    float*    x1        = (float*)alloc((size_t)Nn * 32 * 4);
    float*    x2        = (float*)alloc((size_t)Nn * 32 * 4);
    float*    x3        = (float*)alloc((size_t)Nn * 32 * 4);
    float*    x4        = (float*)alloc((size_t)Nn * 4);
    float*    g         = (float*)alloc((size_t)Nn * 32 * 4);
    float*    pooled    = (float*)alloc((size_t)Gg * Kk * Cc * 4);
    int*      col       = (int*)bucket;

    hipMemsetAsync(bcnt, 0, (size_t)Gg * NSB * 16 * 4, stream);
    k_bucket<<<Ee / 256, 256, 0, stream>>>(ei, bcnt, bucket);
    k_build<<<Gg, 1024, 0, stream>>>(bcnt, bucket, row_start, cnt, dis);

    // layer 1 (128 -> 32)
    k_gemm128x32<<<Nn / 8, 256, 0, stream>>>(x, W1, dis, g);
    k_agg32<<<Nn / 4, 256, 0, stream>>>((const float4*)g, row_start, cnt, col, dis,
                                        (const float4*)b1, (float4*)x1);
    // layer 2 (32 -> 32)
    k_gemm32x32<<<Nn / 8, 256, 0, stream>>>(x1, W2, dis, g);
    k_agg32<<<Nn / 4, 256, 0, stream>>>((const float4*)g, row_start, cnt, col, dis,
                                        (const float4*)b2, (float4*)x2);
    // layer 3 (32 -> 32)
    k_gemm32x32<<<Nn / 8, 256, 0, stream>>>(x2, W3, dis, g);
    k_agg32<<<Nn / 4, 256, 0, stream>>>((const float4*)g, row_start, cnt, col, dis,
                                        (const float4*)b3, (float4*)x3);
    // layer 4 (32 -> 1)
    k_gemm32x1<<<Nn / 8, 256, 0, stream>>>(x3, W4, dis, g);
    k_agg1<<<Nn / 4, 256, 0, stream>>>(g, row_start, cnt, col, dis, b4, x4);

    k_sortpool<<<Gg, 256, 0, stream>>>(x1, x2, x3, x4, pooled);
    k_head<<<Gg, 128, 0, stream>>>(pooled, cw5, cb5, cw6, cb6, fw1, fb1, fw2, fb2, out);
}

// Round 7
// 494.440 us; speedup vs baseline: 2.4612x; 1.2247x over previous
//
#include <hip/hip_runtime.h>
#include <math.h>

#define Nn 102400
#define Gg 256
#define Pp 400
#define Ee 3276800
#define Ff 128
#define Kk 30
#define Cc 97

#define GSTRIDE 16384     // col slots per graph (avg fill 12800, sd ~113)
#define CHUNK 8192        // edges per binsort block

// ---------------- CSR build, phase 1: LDS bin-sort edges by graph ----------------
// Each block: load 8192 edges, count per graph in LDS, reserve contiguous global
// ranges (1 atomic per graph per block), reorder by graph in LDS, stream out.
__global__ void __launch_bounds__(1024) k_binsort(const int* __restrict__ ei,
                                                  int* __restrict__ gcnt,
                                                  unsigned* __restrict__ bucket) {
    __shared__ unsigned reord[CHUNK];        // 32 KB
    __shared__ unsigned char sg[CHUNK];      // 8 KB: slot -> graph
    __shared__ int cntl[Gg];
    __shared__ int ginc[Gg];                 // inclusive prefix
    __shared__ int gex[Gg];                  // exclusive prefix
    __shared__ int gbase[Gg];                // global base from atomicAdd
    __shared__ int cur[Gg];
    int t = threadIdx.x;
    int base = blockIdx.x * CHUNK;
    for (int i = t; i < Gg; i += 1024) cntl[i] = 0;
    __syncthreads();
    unsigned val[8];
    int vg[8];
    bool ok[8];
#pragma unroll
    for (int j = 0; j < 8; j++) {
        int e = base + j * 1024 + t;         // coalesced
        int s = ei[e], d = ei[Ee + e];
        ok[j] = (s != d);
        int gph = d / Pp;
        vg[j] = gph;
        val[j] = (unsigned)s | ((unsigned)(d - gph * Pp) << 17);
        if (ok[j]) atomicAdd(&cntl[gph], 1);
    }
    __syncthreads();
    if (t < Gg) ginc[t] = cntl[t];
    __syncthreads();
    for (int off = 1; off < Gg; off <<= 1) {
        int v = 0;
        if (t < Gg && t >= off) v = ginc[t - off];
        __syncthreads();
        if (t < Gg) ginc[t] += v;
        __syncthreads();
    }
    if (t < Gg) {
        int ex = ginc[t] - cntl[t];
        gex[t] = ex;
        cur[t] = ex;
        gbase[t] = atomicAdd(&gcnt[t], cntl[t]);   // reserve contiguous range
    }
    __syncthreads();
#pragma unroll
    for (int j = 0; j < 8; j++)
        if (ok[j]) {
            int pos = atomicAdd(&cur[vg[j]], 1);
            reord[pos] = val[j];
            sg[pos] = (unsigned char)vg[j];
        }
    __syncthreads();
    int tot = ginc[Gg - 1];
    for (int i = t; i < tot; i += 1024) {          // coalesced within graph runs
        int g = sg[i];
        bucket[g * GSTRIDE + gbase[g] + (i - gex[g])] = reord[i];
    }
}

// ---------------- CSR build, phase 2: per-graph LDS counting sort ----------------
__global__ void __launch_bounds__(1024) k_build(const int* __restrict__ gcnt,
                                                unsigned* __restrict__ bucket, /* also col out */
                                                int* __restrict__ row_start,
                                                int* __restrict__ cnt_g,
                                                float* __restrict__ dis) {
    __shared__ unsigned pairs[GSTRIDE];   // 64 KB stash
    __shared__ int cntl[Pp];
    __shared__ int curl[Pp];
    __shared__ int sc[512];
    int g = blockIdx.x, t = threadIdx.x;
    int tot = gcnt[g];
    if (tot > GSTRIDE) tot = GSTRIDE;
    const unsigned* srcp = bucket + (size_t)g * GSTRIDE;
    for (int i = t; i < tot; i += 1024) pairs[i] = srcp[i];
    for (int i = t; i < Pp; i += 1024) cntl[i] = 0;
    __syncthreads();
    for (int i = t; i < tot; i += 1024) atomicAdd(&cntl[pairs[i] >> 17], 1);
    __syncthreads();
    if (t < 512) sc[t] = (t < Pp) ? cntl[t] : 0;
    __syncthreads();
    for (int off = 1; off < 512; off <<= 1) {
        int v = 0;
        if (t < 512 && t >= off) v = sc[t - off];
        __syncthreads();
        if (t < 512) sc[t] += v;
        __syncthreads();
    }
    if (t < Pp) {
        int c = cntl[t];
        int ex = sc[t] - c;
        curl[t] = ex;
        int n = g * Pp + t;
        row_start[n] = g * GSTRIDE + ex;
        cnt_g[n] = c;
        dis[n] = rsqrtf((float)c + 1.0f);
    }
    __syncthreads();
    int* col = (int*)bucket;              // safe: stash done, block-local region
    for (int i = t; i < tot; i += 1024) {
        unsigned pr = pairs[i];
        int d = pr >> 17;
        int pos = atomicAdd(&curl[d], 1);
        col[g * GSTRIDE + pos] = (int)(pr & 0x1FFFFu);
    }
}

// ---------------- GCN layers ----------------
__global__ void k_gemm128x32(const float* __restrict__ h, const float* __restrict__ W,
                             const float* __restrict__ dis, float* __restrict__ g) {
    __shared__ __align__(16) float Wl[128 * 32];
    __shared__ __align__(16) float hrow[8][128];
    int tid = threadIdx.x;
    for (int i = tid; i < 1024; i += 256)
        ((float4*)Wl)[i] = ((const float4*)W)[i];
    int grp = tid >> 5, c = tid & 31;
    int n = blockIdx.x * 8 + grp;
    ((float4*)hrow[grp])[c] = ((const float4*)(h + n * 128))[c];
    __syncthreads();
    float acc = 0.f;
#pragma unroll 8
    for (int k = 0; k < 128; k++) acc += hrow[grp][k] * Wl[k * 32 + c];
    g[n * 32 + c] = dis[n] * acc;
}

__global__ void k_gemm32x32(const float* __restrict__ h, const float* __restrict__ W,
                            const float* __restrict__ dis, float* __restrict__ g) {
    __shared__ float Wl[32 * 32];
    __shared__ float hrow[8][32];
    int tid = threadIdx.x;
    for (int i = tid; i < 1024; i += 256) Wl[i] = W[i];
    int grp = tid >> 5, c = tid & 31;
    int n = blockIdx.x * 8 + grp;
    hrow[grp][c] = h[n * 32 + c];
    __syncthreads();
    float acc = 0.f;
#pragma unroll
    for (int k = 0; k < 32; k++) acc += hrow[grp][k] * Wl[k * 32 + c];
    g[n * 32 + c] = dis[n] * acc;
}

__global__ void k_gemm32x1(const float* __restrict__ h, const float* __restrict__ W,
                           const float* __restrict__ dis, float* __restrict__ g4) {
    int tid = threadIdx.x;
    int grp = tid >> 5, k = tid & 31;
    int n = blockIdx.x * 8 + grp;
    float v = h[n * 32 + k] * W[k];
#pragma unroll
    for (int m = 16; m >= 1; m >>= 1) v += __shfl_xor(v, m);
    if (k == 0) g4[n] = dis[n] * v;
}

// wave-per-node gather: lane = e_sub*8 + q; 8 edges x float4(4ch) in flight.
__global__ void k_agg32(const float4* __restrict__ gv, const int* __restrict__ row_start,
                        const int* __restrict__ cnt, const int* __restrict__ col,
                        const float* __restrict__ dis, const float4* __restrict__ bv,
                        float4* __restrict__ outv) {
    int tid = threadIdx.x;
    int wave = tid >> 6;
    int lane = tid & 63;
    int e_sub = lane >> 3;
    int q = lane & 7;
    int n = blockIdx.x * 4 + wave;
    int st = row_start[n], cn = cnt[n];

    int colv = (lane < cn) ? col[st + lane] : 0;   // covers up to 64 edges
    int iters = cn < 64 ? cn : 64;

    float4 a0 = make_float4(0.f, 0.f, 0.f, 0.f);
    float4 a1 = make_float4(0.f, 0.f, 0.f, 0.f);
    int base = 0;
    for (; base + 16 <= iters; base += 16) {       // uniform trip count
        int s0 = __shfl(colv, base + e_sub);
        int s1 = __shfl(colv, base + 8 + e_sub);
        float4 v0 = gv[s0 * 8 + q];
        float4 v1 = gv[s1 * 8 + q];
        a0.x += v0.x; a0.y += v0.y; a0.z += v0.z; a0.w += v0.w;
        a1.x += v1.x; a1.y += v1.y; a1.z += v1.z; a1.w += v1.w;
    }
    if (base < iters) {                             // uniform branch; shfls wave-wide
        int i0 = base + e_sub;
        int i1 = base + 8 + e_sub;
        int s0 = __shfl(colv, i0);
        int s1 = __shfl(colv, i1);
        if (i0 < iters) {
            float4 v = gv[s0 * 8 + q];
            a0.x += v.x; a0.y += v.y; a0.z += v.z; a0.w += v.w;
        }
        if (i1 < iters) {
            float4 v = gv[s1 * 8 + q];
            a1.x += v.x; a1.y += v.y; a1.z += v.z; a1.w += v.w;
        }
    }
    for (int j = 64 + e_sub; j < cn; j += 8) {      // rare high-degree tail
        int s = col[st + j];
        float4 v = gv[s * 8 + q];
        a0.x += v.x; a0.y += v.y; a0.z += v.z; a0.w += v.w;
    }
    a0.x += a1.x; a0.y += a1.y; a0.z += a1.z; a0.w += a1.w;
#pragma unroll
    for (int m = 8; m <= 32; m <<= 1) {
        a0.x += __shfl_xor(a0.x, m);
        a0.y += __shfl_xor(a0.y, m);
        a0.z += __shfl_xor(a0.z, m);
        a0.w += __shfl_xor(a0.w, m);
    }
    if (e_sub == 0) {
        float4 self = gv[n * 8 + q];
        float4 bb = bv[q];
        float dn = dis[n];
        float4 r;
        r.x = tanhf(dn * (a0.x + self.x) + bb.x);
        r.y = tanhf(dn * (a0.y + self.y) + bb.y);
        r.z = tanhf(dn * (a0.z + self.z) + bb.z);
        r.w = tanhf(dn * (a0.w + self.w) + bb.w);
        outv[n * 8 + q] = r;
    }
}

__global__ void k_agg1(const float* __restrict__ g4, const int* __restrict__ row_start,
                       const int* __restrict__ cnt, const int* __restrict__ col,
                       const float* __restrict__ dis, const float* __restrict__ b4,
                       float* __restrict__ x4) {
    int tid = threadIdx.x;
    int grp = tid >> 6, l = tid & 63;
    int n = blockIdx.x * 4 + grp;
    int st = row_start[n], cn = cnt[n];
    float acc = 0.f;
    for (int e = l; e < cn; e += 64) acc += g4[col[st + e]];
#pragma unroll
    for (int m = 32; m >= 1; m >>= 1) acc += __shfl_xor(acc, m);
    if (l == 0) x4[n] = tanhf(dis[n] * (acc + g4[n]) + b4[0]);
}

// ---------------- sort pool ----------------
__global__ void k_sortpool(const float* __restrict__ x1, const float* __restrict__ x2,
                           const float* __restrict__ x3, const float* __restrict__ x4,
                           float* __restrict__ pooled) {
    __shared__ float vals[Pp];
    __shared__ int sel[Kk];
    int gid = blockIdx.x;
    int tid = threadIdx.x;
    for (int i = tid; i < Pp; i += 256) vals[i] = x4[gid * Pp + i];
    __syncthreads();
    for (int i = tid; i < Pp; i += 256) {
        float v = vals[i];
        int rank = 0;
        for (int j = 0; j < Pp; j++) {
            float u = vals[j];
            rank += (u > v) || (u == v && j < i);
        }
        if (rank < Kk) sel[rank] = i;
    }
    __syncthreads();
    for (int t = tid; t < Kk * Cc; t += 256) {
        int k = t / Cc, c = t - k * Cc;
        int n = gid * Pp + sel[k];
        float v;
        if (c < 32)      v = x1[n * 32 + c];
        else if (c < 64) v = x2[n * 32 + c - 32];
        else if (c < 96) v = x3[n * 32 + c - 64];
        else             v = x4[n];
        pooled[gid * Kk * Cc + t] = v;
    }
}

// ---------------- CNN + MLP head ----------------
__global__ void k_head(const float* __restrict__ pooled,
                       const float* __restrict__ cw5, const float* __restrict__ cb5,
                       const float* __restrict__ cw6, const float* __restrict__ cb6,
                       const float* __restrict__ fw1, const float* __restrict__ fb1,
                       const float* __restrict__ fw2, const float* __restrict__ fb2,
                       float* __restrict__ out) {
    __shared__ float seq[Kk * Cc];
    __shared__ float w5l[16 * 97];
    __shared__ float t5[16 * 30];
    __shared__ float pl[16 * 15];
    __shared__ float w6l[32 * 16 * 5];
    __shared__ float c6f[352];
    __shared__ float h1[128];
    __shared__ float red[128];
    int gid = blockIdx.x, tid = threadIdx.x;
    for (int i = tid; i < Kk * Cc; i += 128) seq[i] = pooled[gid * Kk * Cc + i];
    for (int i = tid; i < 16 * 97; i += 128) w5l[i] = cw5[i];
    for (int i = tid; i < 2560; i += 128) w6l[i] = cw6[i];
    __syncthreads();
    for (int idx = tid; idx < 480; idx += 128) {
        int ch = idx / 30, t = idx - ch * 30;
        float acc = cb5[ch];
        for (int i = 0; i < 97; i++) acc += w5l[ch * 97 + i] * seq[t * 97 + i];
        t5[ch * 30 + t] = fmaxf(acc, 0.f);
    }
    __syncthreads();
    for (int idx = tid; idx < 240; idx += 128) {
        int ch = idx / 15, t = idx - ch * 15;
        pl[idx] = fmaxf(t5[ch * 30 + 2 * t], t5[ch * 30 + 2 * t + 1]);
    }
    __syncthreads();
    for (int idx = tid; idx < 352; idx += 128) {
        int o = idx / 11, t = idx - o * 11;
        float acc = cb6[o];
        for (int i = 0; i < 16; i++)
            for (int j = 0; j < 5; j++)
                acc += w6l[o * 80 + i * 5 + j] * pl[i * 15 + t + j];
        c6f[o * 11 + t] = fmaxf(acc, 0.f);
    }
    __syncthreads();
    {
        float acc = fb1[tid];
        for (int i = 0; i < 352; i++) acc += c6f[i] * fw1[i * 128 + tid];
        h1[tid] = fmaxf(acc, 0.f);
    }
    __syncthreads();
    red[tid] = h1[tid] * fw2[tid];
    __syncthreads();
    for (int off = 64; off >= 1; off >>= 1) {
        if (tid < off) red[tid] += red[tid + off];
        __syncthreads();
    }
    if (tid == 0) out[gid] = red[0] + fb2[0];
}

extern "C" void kernel_launch(void* const* d_in, const int* in_sizes, int n_in,
                              void* d_out, int out_size, void* d_ws, size_t ws_size,
                              hipStream_t stream) {
    const float* x   = (const float*)d_in[0];
    const int*   ei  = (const int*)d_in[1];
    const float* W1  = (const float*)d_in[3];
    const float* b1  = (const float*)d_in[4];
    const float* W2  = (const float*)d_in[5];
    const float* b2  = (const float*)d_in[6];
    const float* W3  = (const float*)d_in[7];
    const float* b3  = (const float*)d_in[8];
    const float* W4  = (const float*)d_in[9];
    const float* b4  = (const float*)d_in[10];
    const float* cw5 = (const float*)d_in[11];
    const float* cb5 = (const float*)d_in[12];
    const float* cw6 = (const float*)d_in[13];
    const float* cb6 = (const float*)d_in[14];
    const float* fw1 = (const float*)d_in[15];
    const float* fb1 = (const float*)d_in[16];
    const float* fw2 = (const float*)d_in[17];
    const float* fb2 = (const float*)d_in[18];
    float* out = (float*)d_out;

    char* p = (char*)d_ws;
    auto alloc = [&](size_t bytes) {
        char* r = p;
        p += (bytes + 255) & ~size_t(255);
        return r;
    };
    float*    dis       = (float*)alloc((size_t)Nn * 4);
    int*      cnt       = (int*)  alloc((size_t)Nn * 4);
    int*      row_start = (int*)  alloc((size_t)Nn * 4);
    int*      gcnt      = (int*)  alloc((size_t)Gg * 4);
    unsigned* bucket    = (unsigned*)alloc((size_t)Gg * GSTRIDE * 4); // reused as col
    float*    x1        = (float*)alloc((size_t)Nn * 32 * 4);
    float*    x2        = (float*)alloc((size_t)Nn * 32 * 4);
    float*    x3        = (float*)alloc((size_t)Nn * 32 * 4);
    float*    x4        = (float*)alloc((size_t)Nn * 4);
    float*    g         = (float*)alloc((size_t)Nn * 32 * 4);
    float*    pooled    = (float*)alloc((size_t)Gg * Kk * Cc * 4);
    int*      col       = (int*)bucket;

    hipMemsetAsync(gcnt, 0, (size_t)Gg * 4, stream);
    k_binsort<<<Ee / CHUNK, 1024, 0, stream>>>(ei, gcnt, bucket);
    k_build<<<Gg, 1024, 0, stream>>>(gcnt, bucket, row_start, cnt, dis);

    // layer 1 (128 -> 32)
    k_gemm128x32<<<Nn / 8, 256, 0, stream>>>(x, W1, dis, g);
    k_agg32<<<Nn / 4, 256, 0, stream>>>((const float4*)g, row_start, cnt, col, dis,
                                        (const float4*)b1, (float4*)x1);
    // layer 2 (32 -> 32)
    k_gemm32x32<<<Nn / 8, 256, 0, stream>>>(x1, W2, dis, g);
    k_agg32<<<Nn / 4, 256, 0, stream>>>((const float4*)g, row_start, cnt, col, dis,
                                        (const float4*)b2, (float4*)x2);
    // layer 3 (32 -> 32)
    k_gemm32x32<<<Nn / 8, 256, 0, stream>>>(x2, W3, dis, g);
    k_agg32<<<Nn / 4, 256, 0, stream>>>((const float4*)g, row_start, cnt, col, dis,
                                        (const float4*)b3, (float4*)x3);
    // layer 4 (32 -> 1)
    k_gemm32x1<<<Nn / 8, 256, 0, stream>>>(x3, W4, dis, g);
    k_agg1<<<Nn / 4, 256, 0, stream>>>(g, row_start, cnt, col, dis, b4, x4);

    k_sortpool<<<Gg, 256, 0, stream>>>(x1, x2, x3, x4, pooled);
    k_head<<<Gg, 128, 0, stream>>>(pooled, cw5, cb5, cw6, cb6, fw1, fb1, fw2, fb2, out);
}

// Round 8
// 473.076 us; speedup vs baseline: 2.5723x; 1.0452x over previous
//
#include <hip/hip_runtime.h>
#include <math.h>

#define Nn 102400
#define Gg 256
#define Pp 400
#define Ee 3276800
#define Ff 128
#define Kk 30
#define Cc 97

#define GSTRIDE 16384     // col slots per graph (avg fill 12800, sd ~113)
#define CHUNK 8192        // edges per binsort block
#define NBS 400           // binsort blocks

// ---------------- K1: binsort (blocks 0..399)  ||  gemm 128->32 (blocks 400..3599) ----
// binsort: LDS bin edges by graph, reserve contiguous ranges, stream out.
// gemm: hw = x @ W1 (dis applied later in k_build epilogue).
__global__ void __launch_bounds__(1024) k_bs_gemm(const int* __restrict__ ei,
                                                  int* __restrict__ gcnt,
                                                  unsigned* __restrict__ bucket,
                                                  const float* __restrict__ x,
                                                  const float* __restrict__ W1,
                                                  float* __restrict__ hw) {
    __shared__ unsigned reord[CHUNK];        // 32 KB
    __shared__ unsigned char sg[CHUNK];      // 8 KB
    __shared__ int cntl[Gg];
    __shared__ int ginc[Gg];
    __shared__ int gex[Gg];
    __shared__ int gbase[Gg];
    __shared__ int cur[Gg];
    __shared__ __align__(16) float Wl[128 * 32];   // 16 KB
    __shared__ __align__(16) float hrow[32][128];  // 16 KB
    int t = threadIdx.x;
    if (blockIdx.x < NBS) {
        // ---- binsort role ----
        int base = blockIdx.x * CHUNK;
        for (int i = t; i < Gg; i += 1024) cntl[i] = 0;
        __syncthreads();
        unsigned val[8];
        int vg[8];
        bool ok[8];
#pragma unroll
        for (int j = 0; j < 8; j++) {
            int e = base + j * 1024 + t;
            int s = ei[e], d = ei[Ee + e];
            ok[j] = (s != d);
            int gph = d / Pp;
            vg[j] = gph;
            val[j] = (unsigned)s | ((unsigned)(d - gph * Pp) << 17);
            if (ok[j]) atomicAdd(&cntl[gph], 1);
        }
        __syncthreads();
        if (t < Gg) ginc[t] = cntl[t];
        __syncthreads();
        for (int off = 1; off < Gg; off <<= 1) {
            int v = 0;
            if (t < Gg && t >= off) v = ginc[t - off];
            __syncthreads();
            if (t < Gg) ginc[t] += v;
            __syncthreads();
        }
        if (t < Gg) {
            int ex = ginc[t] - cntl[t];
            gex[t] = ex;
            cur[t] = ex;
            gbase[t] = atomicAdd(&gcnt[t], cntl[t]);
        }
        __syncthreads();
#pragma unroll
        for (int j = 0; j < 8; j++)
            if (ok[j]) {
                int pos = atomicAdd(&cur[vg[j]], 1);
                reord[pos] = val[j];
                sg[pos] = (unsigned char)vg[j];
            }
        __syncthreads();
        int tot = ginc[Gg - 1];
        for (int i = t; i < tot; i += 1024) {
            int g = sg[i];
            bucket[g * GSTRIDE + gbase[g] + (i - gex[g])] = reord[i];
        }
    } else {
        // ---- gemm role: 32 rows/block ----
        for (int i = t; i < 1024; i += 1024)
            ((float4*)Wl)[t] = ((const float4*)W1)[t];
        int grp = t >> 5, c = t & 31;
        int n = (blockIdx.x - NBS) * 32 + grp;
        ((float4*)hrow[grp])[c] = ((const float4*)(x + (size_t)n * 128))[c];
        __syncthreads();
        float acc = 0.f;
#pragma unroll 8
        for (int k = 0; k < 128; k++) acc += hrow[grp][k] * Wl[k * 32 + c];
        hw[(size_t)n * 32 + c] = acc;
    }
}

// ---------------- CSR build: per-graph counting sort + dis + scale hw by dis ---------
__global__ void __launch_bounds__(1024) k_build(const int* __restrict__ gcnt,
                                                unsigned* __restrict__ bucket, /* also col out */
                                                int* __restrict__ row_start,
                                                int* __restrict__ cnt_g,
                                                float* __restrict__ dis,
                                                float4* __restrict__ hwv) {
    __shared__ unsigned pairs[GSTRIDE];   // 64 KB stash
    __shared__ int cntl[Pp];
    __shared__ int curl[Pp];
    __shared__ int sc[512];
    int g = blockIdx.x, t = threadIdx.x;
    int tot = gcnt[g];
    if (tot > GSTRIDE) tot = GSTRIDE;
    const unsigned* srcp = bucket + (size_t)g * GSTRIDE;
    for (int i = t; i < tot; i += 1024) pairs[i] = srcp[i];
    for (int i = t; i < Pp; i += 1024) cntl[i] = 0;
    __syncthreads();
    for (int i = t; i < tot; i += 1024) atomicAdd(&cntl[pairs[i] >> 17], 1);
    __syncthreads();
    if (t < 512) sc[t] = (t < Pp) ? cntl[t] : 0;
    __syncthreads();
    for (int off = 1; off < 512; off <<= 1) {
        int v = 0;
        if (t < 512 && t >= off) v = sc[t - off];
        __syncthreads();
        if (t < 512) sc[t] += v;
        __syncthreads();
    }
    if (t < Pp) {
        int c = cntl[t];
        int ex = sc[t] - c;
        curl[t] = ex;
        int n = g * Pp + t;
        row_start[n] = g * GSTRIDE + ex;
        cnt_g[n] = c;
        dis[n] = rsqrtf((float)c + 1.0f);
    }
    __syncthreads();
    // scale hw rows of this graph by dis (fold of g1 = dis (.) (x@W1))
    for (int i = t; i < Pp * 8; i += 1024) {
        int l = i >> 3;
        float dn = rsqrtf((float)cntl[l] + 1.0f);
        float4 v = hwv[(size_t)g * (Pp * 8) + i];
        v.x *= dn; v.y *= dn; v.z *= dn; v.w *= dn;
        hwv[(size_t)g * (Pp * 8) + i] = v;
    }
    int* col = (int*)bucket;              // safe: stash done, block-local region
    for (int i = t; i < tot; i += 1024) {
        unsigned pr = pairs[i];
        int d = pr >> 17;
        int pos = atomicAdd(&curl[d], 1);
        col[g * GSTRIDE + pos] = (int)(pr & 0x1FFFFu);
    }
}

// ---------------- fused agg + next-layer GEMM ----------------
// wave-per-node gather (lane = e_sub*8+q, 8 edges x float4 in flight), butterfly
// reduce leaves the FULL row on every lane (channels 4q..4q+3). Epilogue:
// x_i = tanh(dis*acc+b) written by e_sub==0; then lane(e,q) computes the 4x4
// partial of (x @ Wnext) for out-channels 4e..4e+3, k-block 4q..4q+3; shfl_xor
// over q completes the dot; g_next = dis*(x@Wnext).  NEXT==1: W4 dot -> g4.
template<int NEXT>
__global__ void k_aggF(const float4* __restrict__ gv, const int* __restrict__ row_start,
                       const int* __restrict__ cnt, const int* __restrict__ col,
                       const float* __restrict__ dis, const float4* __restrict__ bv,
                       float4* __restrict__ outv, const float* __restrict__ Wn,
                       float4* __restrict__ gnextv, float* __restrict__ g4) {
    __shared__ __align__(16) float Wl2[32 * 32];
    int tid = threadIdx.x;
    if (NEXT == 32) {
        for (int i = tid; i < 1024; i += 256) Wl2[i] = Wn[i];
        __syncthreads();
    }
    int wave = tid >> 6;
    int lane = tid & 63;
    int e_sub = lane >> 3;
    int q = lane & 7;
    int n = blockIdx.x * 4 + wave;
    int st = row_start[n], cn = cnt[n];

    int colv = (lane < cn) ? col[st + lane] : 0;
    int iters = cn < 64 ? cn : 64;

    float4 a0 = make_float4(0.f, 0.f, 0.f, 0.f);
    float4 a1 = make_float4(0.f, 0.f, 0.f, 0.f);
    int base = 0;
    for (; base + 16 <= iters; base += 16) {       // uniform trip count
        int s0 = __shfl(colv, base + e_sub);
        int s1 = __shfl(colv, base + 8 + e_sub);
        float4 v0 = gv[s0 * 8 + q];
        float4 v1 = gv[s1 * 8 + q];
        a0.x += v0.x; a0.y += v0.y; a0.z += v0.z; a0.w += v0.w;
        a1.x += v1.x; a1.y += v1.y; a1.z += v1.z; a1.w += v1.w;
    }
    if (base < iters) {                             // uniform branch; shfls wave-wide
        int i0 = base + e_sub;
        int i1 = base + 8 + e_sub;
        int s0 = __shfl(colv, i0);
        int s1 = __shfl(colv, i1);
        if (i0 < iters) {
            float4 v = gv[s0 * 8 + q];
            a0.x += v.x; a0.y += v.y; a0.z += v.z; a0.w += v.w;
        }
        if (i1 < iters) {
            float4 v = gv[s1 * 8 + q];
            a1.x += v.x; a1.y += v.y; a1.z += v.z; a1.w += v.w;
        }
    }
    for (int j = 64 + e_sub; j < cn; j += 8) {      // rare high-degree tail
        int s = col[st + j];
        float4 v = gv[s * 8 + q];
        a0.x += v.x; a0.y += v.y; a0.z += v.z; a0.w += v.w;
    }
    a0.x += a1.x; a0.y += a1.y; a0.z += a1.z; a0.w += a1.w;
#pragma unroll
    for (int m = 8; m <= 32; m <<= 1) {             // all lanes end with full sums
        a0.x += __shfl_xor(a0.x, m);
        a0.y += __shfl_xor(a0.y, m);
        a0.z += __shfl_xor(a0.z, m);
        a0.w += __shfl_xor(a0.w, m);
    }
    float dn = dis[n];
    float4 self = gv[n * 8 + q];
    float4 bb = bv[q];
    float4 r;
    r.x = tanhf(dn * (a0.x + self.x) + bb.x);
    r.y = tanhf(dn * (a0.y + self.y) + bb.y);
    r.z = tanhf(dn * (a0.z + self.z) + bb.z);
    r.w = tanhf(dn * (a0.w + self.w) + bb.w);
    if (e_sub == 0) outv[n * 8 + q] = r;
    if (NEXT == 32) {
        const float4* Wv = (const float4*)Wl2;      // [k][8] float4 view
        float4 w0 = Wv[(4 * q + 0) * 8 + e_sub];
        float4 w1 = Wv[(4 * q + 1) * 8 + e_sub];
        float4 w2 = Wv[(4 * q + 2) * 8 + e_sub];
        float4 w3 = Wv[(4 * q + 3) * 8 + e_sub];
        float4 p;
        p.x = r.x * w0.x + r.y * w1.x + r.z * w2.x + r.w * w3.x;
        p.y = r.x * w0.y + r.y * w1.y + r.z * w2.y + r.w * w3.y;
        p.z = r.x * w0.z + r.y * w1.z + r.z * w2.z + r.w * w3.z;
        p.w = r.x * w0.w + r.y * w1.w + r.z * w2.w + r.w * w3.w;
#pragma unroll
        for (int m = 1; m <= 4; m <<= 1) {          // reduce over q (lane bits 0..2)
            p.x += __shfl_xor(p.x, m);
            p.y += __shfl_xor(p.y, m);
            p.z += __shfl_xor(p.z, m);
            p.w += __shfl_xor(p.w, m);
        }
        if (q == 0) {
            p.x *= dn; p.y *= dn; p.z *= dn; p.w *= dn;
            gnextv[n * 8 + e_sub] = p;
        }
    } else {
        float4 w = ((const float4*)Wn)[q];
        float partial = r.x * w.x + r.y * w.y + r.z * w.z + r.w * w.w;
        partial += __shfl_xor(partial, 1);
        partial += __shfl_xor(partial, 2);
        partial += __shfl_xor(partial, 4);
        if (lane == 0) g4[n] = dn * partial;
    }
}

__global__ void k_agg1(const float* __restrict__ g4, const int* __restrict__ row_start,
                       const int* __restrict__ cnt, const int* __restrict__ col,
                       const float* __restrict__ dis, const float* __restrict__ b4,
                       float* __restrict__ x4) {
    int tid = threadIdx.x;
    int grp = tid >> 6, l = tid & 63;
    int n = blockIdx.x * 4 + grp;
    int st = row_start[n], cn = cnt[n];
    float acc = 0.f;
    for (int e = l; e < cn; e += 64) acc += g4[col[st + e]];
#pragma unroll
    for (int m = 32; m >= 1; m >>= 1) acc += __shfl_xor(acc, m);
    if (l == 0) x4[n] = tanhf(dis[n] * (acc + g4[n]) + b4[0]);
}

// ---------------- fused sort-pool + CNN + MLP head (one block per graph) -------------
__global__ void k_sorthead(const float* __restrict__ x1, const float* __restrict__ x2,
                           const float* __restrict__ x3, const float* __restrict__ x4,
                           const float* __restrict__ cw5, const float* __restrict__ cb5,
                           const float* __restrict__ cw6, const float* __restrict__ cb6,
                           const float* __restrict__ fw1, const float* __restrict__ fb1,
                           const float* __restrict__ fw2, const float* __restrict__ fb2,
                           float* __restrict__ out) {
    __shared__ float vals[Pp];
    __shared__ int sel[Kk];
    __shared__ float seq[Kk * Cc];
    __shared__ float w5l[16 * 97];
    __shared__ float t5[16 * 30];
    __shared__ float pl[16 * 15];
    __shared__ float w6l[32 * 16 * 5];
    __shared__ float c6f[352];
    __shared__ float h1[128];
    __shared__ float red[128];
    int gid = blockIdx.x, tid = threadIdx.x;
    for (int i = tid; i < Pp; i += 256) vals[i] = x4[gid * Pp + i];
    for (int i = tid; i < 16 * 97; i += 256) w5l[i] = cw5[i];
    for (int i = tid; i < 2560; i += 256) w6l[i] = cw6[i];
    __syncthreads();
    for (int i = tid; i < Pp; i += 256) {
        float v = vals[i];
        int rank = 0;
        for (int j = 0; j < Pp; j++) {
            float u = vals[j];
            rank += (u > v) || (u == v && j < i);   // stable desc rank
        }
        if (rank < Kk) sel[rank] = i;
    }
    __syncthreads();
    for (int t = tid; t < Kk * Cc; t += 256) {
        int k = t / Cc, c = t - k * Cc;
        int n = gid * Pp + sel[k];
        float v;
        if (c < 32)      v = x1[n * 32 + c];
        else if (c < 64) v = x2[n * 32 + c - 32];
        else if (c < 96) v = x3[n * 32 + c - 64];
        else             v = vals[sel[k]];
        seq[t] = v;
    }
    __syncthreads();
    for (int idx = tid; idx < 480; idx += 256) {
        int ch = idx / 30, t = idx - ch * 30;
        float acc = cb5[ch];
        for (int i = 0; i < 97; i++) acc += w5l[ch * 97 + i] * seq[t * 97 + i];
        t5[ch * 30 + t] = fmaxf(acc, 0.f);
    }
    __syncthreads();
    for (int idx = tid; idx < 240; idx += 256) {
        int ch = idx / 15, t = idx - ch * 15;
        pl[idx] = fmaxf(t5[ch * 30 + 2 * t], t5[ch * 30 + 2 * t + 1]);
    }
    __syncthreads();
    for (int idx = tid; idx < 352; idx += 256) {
        int o = idx / 11, t = idx - o * 11;
        float acc = cb6[o];
        for (int i = 0; i < 16; i++)
            for (int j = 0; j < 5; j++)
                acc += w6l[o * 80 + i * 5 + j] * pl[i * 15 + t + j];
        c6f[o * 11 + t] = fmaxf(acc, 0.f);
    }
    __syncthreads();
    if (tid < 128) {
        float acc = fb1[tid];
        for (int i = 0; i < 352; i++) acc += c6f[i] * fw1[i * 128 + tid];
        h1[tid] = fmaxf(acc, 0.f);
    }
    __syncthreads();
    if (tid < 128) red[tid] = h1[tid] * fw2[tid];
    __syncthreads();
    for (int off = 64; off >= 1; off >>= 1) {
        if (tid < off) red[tid] += red[tid + off];
        __syncthreads();
    }
    if (tid == 0) out[gid] = red[0] + fb2[0];
}

extern "C" void kernel_launch(void* const* d_in, const int* in_sizes, int n_in,
                              void* d_out, int out_size, void* d_ws, size_t ws_size,
                              hipStream_t stream) {
    const float* x   = (const float*)d_in[0];
    const int*   ei  = (const int*)d_in[1];
    const float* W1  = (const float*)d_in[3];
    const float* b1  = (const float*)d_in[4];
    const float* W2  = (const float*)d_in[5];
    const float* b2  = (const float*)d_in[6];
    const float* W3  = (const float*)d_in[7];
    const float* b3  = (const float*)d_in[8];
    const float* W4  = (const float*)d_in[9];
    const float* b4  = (const float*)d_in[10];
    const float* cw5 = (const float*)d_in[11];
    const float* cb5 = (const float*)d_in[12];
    const float* cw6 = (const float*)d_in[13];
    const float* cb6 = (const float*)d_in[14];
    const float* fw1 = (const float*)d_in[15];
    const float* fb1 = (const float*)d_in[16];
    const float* fw2 = (const float*)d_in[17];
    const float* fb2 = (const float*)d_in[18];
    float* out = (float*)d_out;

    char* p = (char*)d_ws;
    auto alloc = [&](size_t bytes) {
        char* r = p;
        p += (bytes + 255) & ~size_t(255);
        return r;
    };
    float*    dis       = (float*)alloc((size_t)Nn * 4);
    int*      cnt       = (int*)  alloc((size_t)Nn * 4);
    int*      row_start = (int*)  alloc((size_t)Nn * 4);
    int*      gcnt      = (int*)  alloc((size_t)Gg * 4);
    unsigned* bucket    = (unsigned*)alloc((size_t)Gg * GSTRIDE * 4); // reused as col
    float*    x1        = (float*)alloc((size_t)Nn * 32 * 4);
    float*    x2        = (float*)alloc((size_t)Nn * 32 * 4);
    float*    x3        = (float*)alloc((size_t)Nn * 32 * 4);
    float*    x4        = (float*)alloc((size_t)Nn * 4);
    float*    g_a       = (float*)alloc((size_t)Nn * 32 * 4);
    float*    g_b       = (float*)alloc((size_t)Nn * 32 * 4);
    int*      col       = (int*)bucket;
    float*    g4        = g_b;              // g_b free by the time aggF<1> runs

    hipMemsetAsync(gcnt, 0, (size_t)Gg * 4, stream);
    k_bs_gemm<<<NBS + Nn / 32, 1024, 0, stream>>>(ei, gcnt, bucket, x, W1, g_a);
    k_build<<<Gg, 1024, 0, stream>>>(gcnt, bucket, row_start, cnt, dis, (float4*)g_a);

    // layer 1: agg(g_a) -> x1, g2 -> g_b
    k_aggF<32><<<Nn / 4, 256, 0, stream>>>((const float4*)g_a, row_start, cnt, col, dis,
                                           (const float4*)b1, (float4*)x1, W2,
                                           (float4*)g_b, nullptr);
    // layer 2: agg(g_b) -> x2, g3 -> g_a
    k_aggF<32><<<Nn / 4, 256, 0, stream>>>((const float4*)g_b, row_start, cnt, col, dis,
                                           (const float4*)b2, (float4*)x2, W3,
                                           (float4*)g_a, nullptr);
    // layer 3: agg(g_a) -> x3, g4 (1ch)
    k_aggF<1><<<Nn / 4, 256, 0, stream>>>((const float4*)g_a, row_start, cnt, col, dis,
                                          (const float4*)b3, (float4*)x3, W4,
                                          nullptr, g4);
    // layer 4 aggregation (scalar channel)
    k_agg1<<<Nn / 4, 256, 0, stream>>>(g4, row_start, cnt, col, dis, b4, x4);

    k_sorthead<<<Gg, 256, 0, stream>>>(x1, x2, x3, x4, cw5, cb5, cw6, cb6,
                                       fw1, fb1, fw2, fb2, out);
}